// Round 12
// baseline (4369.955 us; speedup 1.0000x reference)
//
#include <hip/hip_runtime.h>

typedef short bf16x8 __attribute__((ext_vector_type(8)));
typedef float f32x4 __attribute__((ext_vector_type(4)));

#define MFMA16(a, b, c) __builtin_amdgcn_mfma_f32_16x16x32_bf16(a, b, c, 0, 0, 0)

#define T_ 512
#define C_ 32
#define H_ 256

__device__ __forceinline__ unsigned short f2bf(float f) {
  union { float f; unsigned u; } v; v.f = f;
  return (unsigned short)((v.u + 0x7fffu + ((v.u >> 16) & 1u)) >> 16);
}
__device__ __forceinline__ float fsigmoid(float x) {
  float e = __builtin_amdgcn_exp2f(-1.442695041f * x);
  return __builtin_amdgcn_rcpf(1.0f + e);
}
__device__ __forceinline__ float ftanh(float x) {
  float e = __builtin_amdgcn_exp2f(2.885390082f * x);
  return 1.0f - 2.0f * __builtin_amdgcn_rcpf(e + 1.0f);
}

// ---------- preprocessing: pack W_cat = [Wih | Whh] to bf16, combine biases ----------
// encW/decW: [768][288] bf16 row-major (cols 0..31 = Wih, 32..287 = Whh)
// bias layout (f32): [0..255]=bih_r+bhh_r, [256..511]=bih_z+bhh_z,
//                    [512..767]=bih_n, [768..1023]=bhh_n
__global__ void pack_kernel(
    const float* __restrict__ encWih, const float* __restrict__ encWhh,
    const float* __restrict__ encbih, const float* __restrict__ encbhh,
    const float* __restrict__ decWih, const float* __restrict__ decWhh,
    const float* __restrict__ decbih, const float* __restrict__ decbhh,
    const float* __restrict__ projW, const float* __restrict__ projB,
    unsigned short* __restrict__ encW, unsigned short* __restrict__ decW,
    unsigned short* __restrict__ pW, float* __restrict__ encBias,
    float* __restrict__ decBias, float* __restrict__ pB) {
  int i = blockIdx.x * 256 + threadIdx.x;
  if (i < 768 * 288) {
    int n = i / 288, k = i % 288;
    float ve = (k < 32) ? encWih[n * 32 + k] : encWhh[n * 256 + k - 32];
    float vd = (k < 32) ? decWih[n * 32 + k] : decWhh[n * 256 + k - 32];
    encW[i] = f2bf(ve);
    decW[i] = f2bf(vd);
  }
  if (i < 32 * 256) pW[i] = f2bf(projW[i]);
  if (i < 256) {
    encBias[i]       = encbih[i] + encbhh[i];
    encBias[256 + i] = encbih[256 + i] + encbhh[256 + i];
    encBias[512 + i] = encbih[512 + i];
    encBias[768 + i] = encbhh[512 + i];
    decBias[i]       = decbih[i] + decbhh[i];
    decBias[256 + i] = decbih[256 + i] + decbhh[256 + i];
    decBias[512 + i] = decbih[512 + i];
    decBias[768 + i] = decbhh[512 + i];
  }
  if (i < 32) pB[i] = projB[i];
}

// ---------- GRU: R5 skeleton (exact) with Whh_n chunks 2-7 read from L2 ----------
// 64 blocks x 1024 threads (16 waves, 4/SIMD). Block owns 16 samples.
// Wave w owns cols j = w*16+l15. Regs: Wih(3)+Whh_r(8)+Whh_z(8)+Whh_n{0,1}(2)
// = 21 frags = 84 regs (R10 proved 24-frag split strangles ds_read pipelining).
// Whh_n chunks 2-7: per-lane loop-invariant GLOBAL address, re-read from L2
// each step (6 global_load_dwordx4 off one base, offset: immediates). Moves
// 40% of the LDS-pipe instructions (96 of 240 b128/CU-step) onto the idle
// VMEM path; weights stay L2-resident. LDS: 35.5 KiB (wnl deleted).
// Encoder: 1 barrier/step. Decoder: gates -> B1 -> proj(waves 0-1) -> B2.
// NOTE: h->bf16 must be RNE f2bf; v_cvt_pk_bf16_f32 biased-rounds (R7, 45x err).
__global__ __launch_bounds__(1024) void gru_kernel(
    const float* __restrict__ x,
    const unsigned short* __restrict__ encW,
    const unsigned short* __restrict__ decW,
    const unsigned short* __restrict__ pW,
    const float* __restrict__ encBias,
    const float* __restrict__ decBias,
    const float* __restrict__ pB,
    float* __restrict__ out) {
  __shared__ __align__(16) unsigned short h_lds[2][16][264];  // 16.5 KiB
  __shared__ __align__(16) unsigned short xb[2][16][40];      //  2.5 KiB
  __shared__ __align__(16) unsigned short pwl[32][264];       // 16.5 KiB

  const int tid = (int)threadIdx.x;
  const int wave = tid >> 6, lane = tid & 63;
  const int l15 = lane & 15, l4 = lane >> 4;
  const int ko = l4 * 8;
  const int gbase = (int)blockIdx.x * 16;
  const int j = wave * 16 + l15;

  for (int i = tid; i < 2 * 16 * 264 / 2; i += 1024) ((unsigned*)h_lds)[i] = 0;
  for (int i = tid; i < 2 * 16 * 40 / 2; i += 1024) ((unsigned*)xb)[i] = 0;
  {
    int n = tid >> 5, slot = tid & 31;
    *(bf16x8*)&pwl[n][slot * 8] = *(const bf16x8*)(pW + n * 256 + slot * 8);
  }

  const float* xLane = x + (size_t)(gbase + (tid >> 5)) * (T_ * C_) + (tid & 31);
  float* outLane = out + (size_t)(gbase + l4 * 4) * (T_ * C_) + wave * 16 + l15;
  const float pbias = (wave < 2) ? pB[wave * 16 + l15] : 0.f;
  f32x4 hreg = {0.f, 0.f, 0.f, 0.f};

  bf16x8 wi0, wi1, wi2, wr[8], wz[8], wn2[2];
  const unsigned short* wnp;  // loop-invariant per-lane base for Whh_n chunks 2-7

  auto loadW = [&](const unsigned short* Wp) {
    wi0 = *(const bf16x8*)(Wp + (size_t)j * 288 + ko);
    wi1 = *(const bf16x8*)(Wp + (size_t)(j + 256) * 288 + ko);
    wi2 = *(const bf16x8*)(Wp + (size_t)(j + 512) * 288 + ko);
#pragma unroll
    for (int kk = 0; kk < 8; ++kk) {
      wr[kk] = *(const bf16x8*)(Wp + (size_t)j * 288 + 32 + kk * 32 + ko);
      wz[kk] = *(const bf16x8*)(Wp + (size_t)(j + 256) * 288 + 32 + kk * 32 + ko);
    }
#pragma unroll
    for (int kk = 0; kk < 2; ++kk)
      wn2[kk] = *(const bf16x8*)(Wp + (size_t)(j + 512) * 288 + 32 + kk * 32 + ko);
    wnp = Wp + (size_t)(j + 512) * 288 + 32 + 2 * 32 + ko;  // chunk 2 base
  };

  // ================= encoder =================
  loadW(encW);
  float br = encBias[j], bz = encBias[256 + j];
  float bin = encBias[512 + j], bhn = encBias[768 + j];
  if (tid < 512) xb[0][tid >> 5][tid & 31] = f2bf(xLane[0]);  // stage x_0
  __syncthreads();

  for (int t = 0; t < T_; ++t) {
    if (t < T_ - 1 && tid < 512)  // stage x_{t+1} into the other buffer
      xb[(t + 1) & 1][tid >> 5][tid & 31] = f2bf(xLane[(size_t)(t + 1) * C_]);

    // issue the 6 L2 weight loads early; consumed by the last 6 n-MFMAs
    bf16x8 g2 = *(const bf16x8*)(wnp + 0 * 32);
    bf16x8 g3 = *(const bf16x8*)(wnp + 1 * 32);
    bf16x8 g4 = *(const bf16x8*)(wnp + 2 * 32);
    bf16x8 g5 = *(const bf16x8*)(wnp + 3 * 32);
    bf16x8 g6 = *(const bf16x8*)(wnp + 4 * 32);
    bf16x8 g7 = *(const bf16x8*)(wnp + 5 * 32);

    f32x4 accr = {br, br, br, br}, accz = {bz, bz, bz, bz};
    f32x4 accin = {bin, bin, bin, bin}, acchn = {bhn, bhn, bhn, bhn};
    {  // x chunk (K=32)
      bf16x8 a0 = *(const bf16x8*)&xb[t & 1][l15][ko];
      accr  = MFMA16(a0, wi0, accr);
      accz  = MFMA16(a0, wi1, accz);
      accin = MFMA16(a0, wi2, accin);
    }
#pragma unroll
    for (int kk = 0; kk < 8; ++kk) {  // h part (K=256)
      bf16x8 ah = *(const bf16x8*)&h_lds[t & 1][l15][kk * 32 + ko];
      accr = MFMA16(ah, wr[kk], accr);
      accz = MFMA16(ah, wz[kk], accz);
      bf16x8 wnk = (kk == 0) ? wn2[0] : (kk == 1) ? wn2[1] :
                   (kk == 2) ? g2 : (kk == 3) ? g3 : (kk == 4) ? g4 :
                   (kk == 5) ? g5 : (kk == 6) ? g6 : g7;
      acchn = MFMA16(ah, wnk, acchn);
    }
#pragma unroll
    for (int r = 0; r < 4; ++r) {
      float rg = fsigmoid(accr[r]);
      float zg = fsigmoid(accz[r]);
      float ng = ftanh(accin[r] + rg * acchn[r]);
      float hv = zg * (hreg[r] - ng) + ng;
      hreg[r] = hv;
      h_lds[(t + 1) & 1][l4 * 4 + r][j] = f2bf(hv);
    }
    __syncthreads();  // h[(t+1)&1] + xb[(t+1)&1] visible; step reads done
  }

  // ================= decoder (R5-proven schedule) =================
  // h_enc is in h_lds[0] (=h^0_dec) and hreg.
  loadW(decW);
  br = decBias[j]; bz = decBias[256 + j];
  bin = decBias[512 + j]; bhn = decBias[768 + j];
  if (tid < 320) ((unsigned*)xb)[tid] = 0;  // xb[0] = start token zeros
  __syncthreads();

  for (int t = 0; t < T_; ++t) {
    // entry: h_lds[t&1] = h^t, xb[0] = x_t (both barrier-published)
    bf16x8 g2 = *(const bf16x8*)(wnp + 0 * 32);
    bf16x8 g3 = *(const bf16x8*)(wnp + 1 * 32);
    bf16x8 g4 = *(const bf16x8*)(wnp + 2 * 32);
    bf16x8 g5 = *(const bf16x8*)(wnp + 3 * 32);
    bf16x8 g6 = *(const bf16x8*)(wnp + 4 * 32);
    bf16x8 g7 = *(const bf16x8*)(wnp + 5 * 32);

    f32x4 accr = {br, br, br, br}, accz = {bz, bz, bz, bz};
    f32x4 accin = {bin, bin, bin, bin}, acchn = {bhn, bhn, bhn, bhn};
    {  // x chunk
      bf16x8 a0 = *(const bf16x8*)&xb[0][l15][ko];
      accr  = MFMA16(a0, wi0, accr);
      accz  = MFMA16(a0, wi1, accz);
      accin = MFMA16(a0, wi2, accin);
    }
#pragma unroll
    for (int kk = 0; kk < 8; ++kk) {
      bf16x8 ah = *(const bf16x8*)&h_lds[t & 1][l15][kk * 32 + ko];
      accr = MFMA16(ah, wr[kk], accr);
      accz = MFMA16(ah, wz[kk], accz);
      bf16x8 wnk = (kk == 0) ? wn2[0] : (kk == 1) ? wn2[1] :
                   (kk == 2) ? g2 : (kk == 3) ? g3 : (kk == 4) ? g4 :
                   (kk == 5) ? g5 : (kk == 6) ? g6 : g7;
      acchn = MFMA16(ah, wnk, acchn);
    }
#pragma unroll
    for (int r = 0; r < 4; ++r) {
      float rg = fsigmoid(accr[r]);
      float zg = fsigmoid(accz[r]);
      float ng = ftanh(accin[r] + rg * acchn[r]);
      float hv = zg * (hreg[r] - ng) + ng;
      hreg[r] = hv;
      h_lds[(t + 1) & 1][l4 * 4 + r][j] = f2bf(hv);
    }
    __syncthreads();  // B1: h^{t+1} visible; xb[0]/h_lds[t&1] reads done

    if (wave < 2) {  // pred_t = proj(h^{t+1}) -> out + next-step input
      f32x4 pa = {pbias, pbias, pbias, pbias};
      const int pn = wave * 16 + l15;
#pragma unroll
      for (int kk = 0; kk < 8; ++kk) {
        bf16x8 ah = *(const bf16x8*)&h_lds[(t + 1) & 1][l15][kk * 32 + ko];
        bf16x8 bw = *(const bf16x8*)&pwl[pn][kk * 32 + ko];
        pa = MFMA16(ah, bw, pa);
      }
#pragma unroll
      for (int r = 0; r < 4; ++r) {
        outLane[(size_t)r * (T_ * C_) + t * C_] = pa[r];
        xb[0][l4 * 4 + r][pn] = f2bf(pa[r]);  // x_{t+1}
      }
    }
    __syncthreads();  // B2: xb[0] (x_{t+1}) visible to all waves
  }
}

extern "C" void kernel_launch(void* const* d_in, const int* in_sizes, int n_in,
                              void* d_out, int out_size, void* d_ws, size_t ws_size,
                              hipStream_t stream) {
  const float* x      = (const float*)d_in[0];
  const float* encWih = (const float*)d_in[1];
  const float* encWhh = (const float*)d_in[2];
  const float* encbih = (const float*)d_in[3];
  const float* encbhh = (const float*)d_in[4];
  const float* decWih = (const float*)d_in[5];
  const float* decWhh = (const float*)d_in[6];
  const float* decbih = (const float*)d_in[7];
  const float* decbhh = (const float*)d_in[8];
  const float* projW  = (const float*)d_in[9];
  const float* projB  = (const float*)d_in[10];

  char* ws = (char*)d_ws;
  unsigned short* encW = (unsigned short*)(ws);             // 442368 B
  unsigned short* decW = (unsigned short*)(ws + 442368);    // 442368 B
  unsigned short* pW   = (unsigned short*)(ws + 884736);    // 16384 B
  float* encBias = (float*)(ws + 901120);                   // 4096 B
  float* decBias = (float*)(ws + 905216);                   // 4096 B
  float* pB      = (float*)(ws + 909312);                   // 128 B

  pack_kernel<<<864, 256, 0, stream>>>(encWih, encWhh, encbih, encbhh,
                                       decWih, decWhh, decbih, decbhh,
                                       projW, projB,
                                       encW, decW, pW, encBias, decBias, pB);
  gru_kernel<<<64, 1024, 0, stream>>>(x, encW, decW, pW, encBias, decBias, pB,
                                      (float*)d_out);
}

// Round 13
// 2615.453 us; speedup vs baseline: 1.6708x; 1.6708x over previous
//
#include <hip/hip_runtime.h>

typedef short bf16x8 __attribute__((ext_vector_type(8)));
typedef float f32x4 __attribute__((ext_vector_type(4)));

#define MFMA16(a, b, c) __builtin_amdgcn_mfma_f32_16x16x32_bf16(a, b, c, 0, 0, 0)

#define T_ 512
#define C_ 32
#define H_ 256

__device__ __forceinline__ unsigned short f2bf(float f) {
  union { float f; unsigned u; } v; v.f = f;
  return (unsigned short)((v.u + 0x7fffu + ((v.u >> 16) & 1u)) >> 16);
}
__device__ __forceinline__ float fsigmoid(float x) {
  float e = __builtin_amdgcn_exp2f(-1.442695041f * x);
  return __builtin_amdgcn_rcpf(1.0f + e);
}
__device__ __forceinline__ float ftanh(float x) {
  float e = __builtin_amdgcn_exp2f(2.885390082f * x);
  return 1.0f - 2.0f * __builtin_amdgcn_rcpf(e + 1.0f);
}

// ---------- preprocessing: pack W_cat = [Wih | Whh] to bf16, combine biases ----------
// encW/decW: [768][288] bf16 row-major (cols 0..31 = Wih, 32..287 = Whh)
// bias layout (f32): [0..255]=bih_r+bhh_r, [256..511]=bih_z+bhh_z,
//                    [512..767]=bih_n, [768..1023]=bhh_n
__global__ void pack_kernel(
    const float* __restrict__ encWih, const float* __restrict__ encWhh,
    const float* __restrict__ encbih, const float* __restrict__ encbhh,
    const float* __restrict__ decWih, const float* __restrict__ decWhh,
    const float* __restrict__ decbih, const float* __restrict__ decbhh,
    const float* __restrict__ projW, const float* __restrict__ projB,
    unsigned short* __restrict__ encW, unsigned short* __restrict__ decW,
    unsigned short* __restrict__ pW, float* __restrict__ encBias,
    float* __restrict__ decBias, float* __restrict__ pB) {
  int i = blockIdx.x * 256 + threadIdx.x;
  if (i < 768 * 288) {
    int n = i / 288, k = i % 288;
    float ve = (k < 32) ? encWih[n * 32 + k] : encWhh[n * 256 + k - 32];
    float vd = (k < 32) ? decWih[n * 32 + k] : decWhh[n * 256 + k - 32];
    encW[i] = f2bf(ve);
    decW[i] = f2bf(vd);
  }
  if (i < 32 * 256) pW[i] = f2bf(projW[i]);
  if (i < 256) {
    encBias[i]       = encbih[i] + encbhh[i];
    encBias[256 + i] = encbih[256 + i] + encbhh[256 + i];
    encBias[512 + i] = encbih[512 + i];
    encBias[768 + i] = encbhh[512 + i];
    decBias[i]       = decbih[i] + decbhh[i];
    decBias[256 + i] = decbih[256 + i] + decbhh[256 + i];
    decBias[512 + i] = decbih[512 + i];
    decBias[768 + i] = decbhh[512 + i];
  }
  if (i < 32) pB[i] = projB[i];
}

// ---------- GRU: R5 skeleton (exact) + one-step-ahead x prefetch ----------
// 64 blocks x 1024 threads (16 waves, 4/SIMD). Block owns 16 samples.
// Wave w owns cols j = w*16+l15. Regs: Wih(3)+Whh_r(8)+Whh_z(8)+Whh_n{0,1}(2)
// = 21 frags = 84 regs (R10: 24-frag split strangles ds_read pipelining;
// R12: per-step L2 re-reads expose vmcnt latency — both refuted).
// Whh_n chunks 2-7 in LDS wnl (stride 80B). NO swizzle (R9 refuted).
// NEW vs R5: encoder x-staging prefetches x_{t+1} into a register a full
// step ahead, so the step-top ds_write has zero vmcnt wait (removes the
// 8-wave global-load stall that skews barrier arrival).
// Encoder: 1 barrier/step. Decoder: gates -> B1 -> proj(waves 0-1) -> B2.
// NOTE: h->bf16 must be RNE f2bf; v_cvt_pk_bf16_f32 biased-rounds (R7).
__global__ __launch_bounds__(1024) void gru_kernel(
    const float* __restrict__ x,
    const unsigned short* __restrict__ encW,
    const unsigned short* __restrict__ decW,
    const unsigned short* __restrict__ pW,
    const float* __restrict__ encBias,
    const float* __restrict__ decBias,
    const float* __restrict__ pB,
    float* __restrict__ out) {
  __shared__ __align__(16) unsigned short wnl[6][256][40];    // 120.0 KiB
  __shared__ __align__(16) unsigned short h_lds[2][16][264];  //  16.5 KiB
  __shared__ __align__(16) unsigned short xb[2][16][40];      //   2.5 KiB
  __shared__ __align__(16) unsigned short pwl[32][264];       //  16.5 KiB

  const int tid = (int)threadIdx.x;
  const int wave = tid >> 6, lane = tid & 63;
  const int l15 = lane & 15, l4 = lane >> 4;
  const int ko = l4 * 8;
  const int gbase = (int)blockIdx.x * 16;
  const int j = wave * 16 + l15;

  for (int i = tid; i < 2 * 16 * 264 / 2; i += 1024) ((unsigned*)h_lds)[i] = 0;
  for (int i = tid; i < 2 * 16 * 40 / 2; i += 1024) ((unsigned*)xb)[i] = 0;
  {
    int n = tid >> 5, slot = tid & 31;
    *(bf16x8*)&pwl[n][slot * 8] = *(const bf16x8*)(pW + n * 256 + slot * 8);
  }

  const float* xLane = x + (size_t)(gbase + (tid >> 5)) * (T_ * C_) + (tid & 31);
  float* outLane = out + (size_t)(gbase + l4 * 4) * (T_ * C_) + wave * 16 + l15;
  const float pbias = (wave < 2) ? pB[wave * 16 + l15] : 0.f;
  f32x4 hreg = {0.f, 0.f, 0.f, 0.f};

  bf16x8 wi0, wi1, wi2, wr[8], wz[8], wn2[2];

  auto loadW = [&](const unsigned short* Wp) {
    wi0 = *(const bf16x8*)(Wp + (size_t)j * 288 + ko);
    wi1 = *(const bf16x8*)(Wp + (size_t)(j + 256) * 288 + ko);
    wi2 = *(const bf16x8*)(Wp + (size_t)(j + 512) * 288 + ko);
#pragma unroll
    for (int kk = 0; kk < 8; ++kk) {
      wr[kk] = *(const bf16x8*)(Wp + (size_t)j * 288 + 32 + kk * 32 + ko);
      wz[kk] = *(const bf16x8*)(Wp + (size_t)(j + 256) * 288 + 32 + kk * 32 + ko);
    }
#pragma unroll
    for (int kk = 0; kk < 2; ++kk)
      wn2[kk] = *(const bf16x8*)(Wp + (size_t)(j + 512) * 288 + 32 + kk * 32 + ko);
    for (int i = tid; i < 6 * 256 * 4; i += 1024) {  // Whh_n chunks 2..7 -> LDS
      int kc = i >> 10, rem = i & 1023;
      int jj = rem >> 2, kc2 = rem & 3;
      *(bf16x8*)&wnl[kc][jj][kc2 * 8] =
          *(const bf16x8*)(Wp + (size_t)(jj + 512) * 288 + 32 + (kc + 2) * 32 + kc2 * 8);
    }
  };

  // ================= encoder =================
  loadW(encW);
  float br = encBias[j], bz = encBias[256 + j];
  float bin = encBias[512 + j], bhn = encBias[768 + j];
  float xv = 0.f;
  if (tid < 512) {
    xb[0][tid >> 5][tid & 31] = f2bf(xLane[0]);  // stage x_0
    xv = xLane[C_];                              // prefetch x_1
  }
  __syncthreads();

  for (int t = 0; t < T_; ++t) {
    if (t < T_ - 1 && tid < 512) {
      // stage x_{t+1} from the prefetch register (no vmcnt wait here),
      // then issue the x_{t+2} load — consumed one full step later.
      xb[(t + 1) & 1][tid >> 5][tid & 31] = f2bf(xv);
      if (t < T_ - 2) xv = xLane[(size_t)(t + 2) * C_];
    }

    f32x4 accr = {br, br, br, br}, accz = {bz, bz, bz, bz};
    f32x4 accin = {bin, bin, bin, bin}, acchn = {bhn, bhn, bhn, bhn};
    {  // x chunk (K=32)
      bf16x8 a0 = *(const bf16x8*)&xb[t & 1][l15][ko];
      accr  = MFMA16(a0, wi0, accr);
      accz  = MFMA16(a0, wi1, accz);
      accin = MFMA16(a0, wi2, accin);
    }
#pragma unroll
    for (int kk = 0; kk < 8; ++kk) {  // h part (K=256)
      bf16x8 ah = *(const bf16x8*)&h_lds[t & 1][l15][kk * 32 + ko];
      accr = MFMA16(ah, wr[kk], accr);
      accz = MFMA16(ah, wz[kk], accz);
      bf16x8 wnk = (kk < 2) ? wn2[kk] : *(const bf16x8*)&wnl[kk - 2][j][ko];
      acchn = MFMA16(ah, wnk, acchn);
    }
#pragma unroll
    for (int r = 0; r < 4; ++r) {
      float rg = fsigmoid(accr[r]);
      float zg = fsigmoid(accz[r]);
      float ng = ftanh(accin[r] + rg * acchn[r]);
      float hv = zg * (hreg[r] - ng) + ng;
      hreg[r] = hv;
      h_lds[(t + 1) & 1][l4 * 4 + r][j] = f2bf(hv);
    }
    __syncthreads();  // h[(t+1)&1] + xb[(t+1)&1] visible; step reads done
  }

  // ================= decoder (R5-proven schedule) =================
  // h_enc is in h_lds[0] (=h^0_dec) and hreg.
  loadW(decW);
  br = decBias[j]; bz = decBias[256 + j];
  bin = decBias[512 + j]; bhn = decBias[768 + j];
  if (tid < 320) ((unsigned*)xb)[tid] = 0;  // xb[0] = start token zeros
  __syncthreads();

  for (int t = 0; t < T_; ++t) {
    // entry: h_lds[t&1] = h^t, xb[0] = x_t (both barrier-published)
    f32x4 accr = {br, br, br, br}, accz = {bz, bz, bz, bz};
    f32x4 accin = {bin, bin, bin, bin}, acchn = {bhn, bhn, bhn, bhn};
    {  // x chunk
      bf16x8 a0 = *(const bf16x8*)&xb[0][l15][ko];
      accr  = MFMA16(a0, wi0, accr);
      accz  = MFMA16(a0, wi1, accz);
      accin = MFMA16(a0, wi2, accin);
    }
#pragma unroll
    for (int kk = 0; kk < 8; ++kk) {
      bf16x8 ah = *(const bf16x8*)&h_lds[t & 1][l15][kk * 32 + ko];
      accr = MFMA16(ah, wr[kk], accr);
      accz = MFMA16(ah, wz[kk], accz);
      bf16x8 wnk = (kk < 2) ? wn2[kk] : *(const bf16x8*)&wnl[kk - 2][j][ko];
      acchn = MFMA16(ah, wnk, acchn);
    }
#pragma unroll
    for (int r = 0; r < 4; ++r) {
      float rg = fsigmoid(accr[r]);
      float zg = fsigmoid(accz[r]);
      float ng = ftanh(accin[r] + rg * acchn[r]);
      float hv = zg * (hreg[r] - ng) + ng;
      hreg[r] = hv;
      h_lds[(t + 1) & 1][l4 * 4 + r][j] = f2bf(hv);
    }
    __syncthreads();  // B1: h^{t+1} visible; xb[0]/h_lds[t&1] reads done

    if (wave < 2) {  // pred_t = proj(h^{t+1}) -> out + next-step input
      f32x4 pa = {pbias, pbias, pbias, pbias};
      const int pn = wave * 16 + l15;
#pragma unroll
      for (int kk = 0; kk < 8; ++kk) {
        bf16x8 ah = *(const bf16x8*)&h_lds[(t + 1) & 1][l15][kk * 32 + ko];
        bf16x8 bw = *(const bf16x8*)&pwl[pn][kk * 32 + ko];
        pa = MFMA16(ah, bw, pa);
      }
#pragma unroll
      for (int r = 0; r < 4; ++r) {
        outLane[(size_t)r * (T_ * C_) + t * C_] = pa[r];
        xb[0][l4 * 4 + r][pn] = f2bf(pa[r]);  // x_{t+1}
      }
    }
    __syncthreads();  // B2: xb[0] (x_{t+1}) visible to all waves
  }
}

extern "C" void kernel_launch(void* const* d_in, const int* in_sizes, int n_in,
                              void* d_out, int out_size, void* d_ws, size_t ws_size,
                              hipStream_t stream) {
  const float* x      = (const float*)d_in[0];
  const float* encWih = (const float*)d_in[1];
  const float* encWhh = (const float*)d_in[2];
  const float* encbih = (const float*)d_in[3];
  const float* encbhh = (const float*)d_in[4];
  const float* decWih = (const float*)d_in[5];
  const float* decWhh = (const float*)d_in[6];
  const float* decbih = (const float*)d_in[7];
  const float* decbhh = (const float*)d_in[8];
  const float* projW  = (const float*)d_in[9];
  const float* projB  = (const float*)d_in[10];

  char* ws = (char*)d_ws;
  unsigned short* encW = (unsigned short*)(ws);             // 442368 B
  unsigned short* decW = (unsigned short*)(ws + 442368);    // 442368 B
  unsigned short* pW   = (unsigned short*)(ws + 884736);    // 16384 B
  float* encBias = (float*)(ws + 901120);                   // 4096 B
  float* decBias = (float*)(ws + 905216);                   // 4096 B
  float* pB      = (float*)(ws + 909312);                   // 128 B

  pack_kernel<<<864, 256, 0, stream>>>(encWih, encWhh, encbih, encbhh,
                                       decWih, decWhh, decbih, decbhh,
                                       projW, projB,
                                       encW, decW, pW, encBias, decBias, pB);
  gru_kernel<<<64, 1024, 0, stream>>>(x, encW, decW, pW, encBias, decBias, pB,
                                      (float*)d_out);
}